// Round 3
// baseline (483.598 us; speedup 1.0000x reference)
//
#include <hip/hip_runtime.h>

#define NMS_TH 0.7

// ---------------------------------------------------------------------------
// Kernel A: per-box fp64 corners (CCW) + fp64 areas + fp32 AABB + fp32 area.
// Block 0 / thread 0 also zeroes the candidate counter.
// ---------------------------------------------------------------------------
__global__ void corners_kernel(const float* __restrict__ boxes,
                               double* __restrict__ cor,    // N*8
                               double* __restrict__ areas,  // N
                               float* __restrict__ aabb,    // 5*N: xmin,xmax,ymin,ymax,areaf
                               unsigned int* __restrict__ counter,
                               int N) {
    int i = blockIdx.x * blockDim.x + threadIdx.x;
    if (blockIdx.x == 0 && threadIdx.x == 0) *counter = 0u;
    if (i >= N) return;
    double xc = boxes[i * 5 + 0];
    double yc = boxes[i * 5 + 1];
    double w  = boxes[i * 5 + 2];
    double h  = boxes[i * 5 + 3];
    double t  = boxes[i * 5 + 4];
    double th = t * 0.017453292519943295;  // pi/180
    double c = cos(th), s = sin(th);
    const double lx[4] = {0.5, -0.5, -0.5, 0.5};
    const double ly[4] = {0.5, 0.5, -0.5, -0.5};
    double xmn = 1e30, xmx = -1e30, ymn = 1e30, ymx = -1e30;
#pragma unroll
    for (int k = 0; k < 4; ++k) {
        double x = xc + lx[k] * w * c - ly[k] * h * s;
        double y = yc + lx[k] * w * s + ly[k] * h * c;
        cor[i * 8 + k * 2 + 0] = x;
        cor[i * 8 + k * 2 + 1] = y;
        xmn = fmin(xmn, x); xmx = fmax(xmx, x);
        ymn = fmin(ymn, y); ymx = fmax(ymx, y);
    }
    areas[i] = w * h;
    aabb[0 * N + i] = (float)xmn;
    aabb[1 * N + i] = (float)xmx;
    aabb[2 * N + i] = (float)ymn;
    aabb[3 * N + i] = (float)ymx;
    aabb[4 * N + i] = (float)(w * h);
}

// ---------------------------------------------------------------------------
// Exact convex-quad intersection area via Green's theorem (fp64, static).
// ---------------------------------------------------------------------------
__device__ __forceinline__ double clip_sum(const double* __restrict__ px,
                                           const double* __restrict__ py,
                                           const double* __restrict__ qx,
                                           const double* __restrict__ qy) {
    double acc = 0.0;
#pragma unroll
    for (int e = 0; e < 4; ++e) {
        double x0 = px[e], y0 = py[e];
        double x1 = px[(e + 1) & 3], y1 = py[(e + 1) & 3];
        double dx = x1 - x0, dy = y1 - y0;
        double t0 = 0.0, t1 = 1.0;
        bool empty = false;
#pragma unroll
        for (int f = 0; f < 4; ++f) {
            double ex0 = qx[f], ey0 = qy[f];
            double ex1 = qx[(f + 1) & 3], ey1 = qy[(f + 1) & 3];
            double edx = ex1 - ex0, edy = ey1 - ey0;
            double f0 = edx * (y0 - ey0) - edy * (x0 - ex0);
            double f1 = edx * (y1 - ey0) - edy * (x1 - ex0);
            double df = f1 - f0;
            if (df > 0.0) {
                t0 = fmax(t0, -f0 / df);
            } else if (df < 0.0) {
                t1 = fmin(t1, -f0 / df);
            } else if (f0 < 0.0) {
                empty = true;
            }
        }
        if (!empty && t0 < t1) {
            double ax = x0 + t0 * dx, ay = y0 + t0 * dy;
            double bx = x0 + t1 * dx, by = y0 + t1 * dy;
            acc += ax * by - bx * ay;
        }
    }
    return acc;
}

__device__ __forceinline__ bool exact_suppress(const double* __restrict__ cor,
                                               const double* __restrict__ areas,
                                               int i, int j) {
    double px[4], py[4], qx[4], qy[4];
#pragma unroll
    for (int k = 0; k < 4; ++k) {
        px[k] = cor[i * 8 + k * 2 + 0];
        py[k] = cor[i * 8 + k * 2 + 1];
        qx[k] = cor[j * 8 + k * 2 + 0];
        qy[k] = cor[j * 8 + k * 2 + 1];
    }
    double inter = 0.5 * (clip_sum(px, py, qx, qy) + clip_sum(qx, qy, px, py));
    inter = fmax(inter, 0.0);
    double uni = areas[i] + areas[j] - inter;
    double iou = inter / fmax(uni, 1e-8);
    return iou > NMS_TH;
}

// ---------------------------------------------------------------------------
// Kernel B1: fp32 AABB upper-bound filter + compaction.
// Grid = N blocks (block = row i) x 256 threads (4 waves). Wave w handles
// words w, w+4, ..., w+28. Exact-safe prune: iou <= AABB_inter/(S-AABB_inter);
// candidate iff 1.699*AABB_inter >= 0.699*S (guard band 1e-3 vs 0.7).
// Also zeroes the mask word (phase 2 atomicOr's exact bits in).
// ---------------------------------------------------------------------------
__global__ __launch_bounds__(256) void bound_kernel(
    const float* __restrict__ aabb, unsigned long long* __restrict__ mask,
    unsigned int* __restrict__ list, unsigned int* __restrict__ counter,
    int N, int words, unsigned int cap) {
    int i = blockIdx.x;
    int lane = threadIdx.x & 63;
    int wave = threadIdx.x >> 6;

    float ixmn = aabb[0 * N + i], ixmx = aabb[1 * N + i];
    float iymn = aabb[2 * N + i], iymx = aabb[3 * N + i];
    float iaf = aabb[4 * N + i];

    for (int w = wave; w < words; w += 4) {
        int j = w * 64 + lane;
        bool cand = false;
        if (j < N && j > i) {
            float iw = fminf(ixmx, aabb[1 * N + j]) - fmaxf(ixmn, aabb[0 * N + j]);
            float ih = fminf(iymx, aabb[3 * N + j]) - fmaxf(iymn, aabb[2 * N + j]);
            if (iw > 0.0f && ih > 0.0f) {
                float ia = iw * ih;
                cand = 1.699f * ia >= 0.699f * (iaf + aabb[4 * N + j]);
            }
        }
        unsigned long long b = __ballot(cand);
        if (lane == 0) mask[(size_t)i * words + w] = 0ULL;
        if (b) {
            unsigned int basepos = 0;
            if (lane == 0) basepos = atomicAdd(counter, (unsigned int)__popcll(b));
            basepos = __shfl((int)basepos, 0);
            if (cand) {
                unsigned int ofs =
                    (unsigned int)__popcll(b & ((1ULL << lane) - 1ULL));
                unsigned int idx = basepos + ofs;
                if (idx < cap)
                    list[idx] = ((unsigned int)i << 11) | (unsigned int)j;
            }
        }
    }
}

// ---------------------------------------------------------------------------
// Kernel B2: exact fp64 IoU on the dense survivor list; atomicOr mask bits.
// ---------------------------------------------------------------------------
__global__ __launch_bounds__(256) void exact_kernel(
    const double* __restrict__ cor, const double* __restrict__ areas,
    const unsigned int* __restrict__ list,
    const unsigned int* __restrict__ counter,
    unsigned long long* __restrict__ mask, int words, unsigned int cap) {
    unsigned int n = *counter;
    if (n > cap) n = cap;
    for (unsigned int idx = blockIdx.x * blockDim.x + threadIdx.x; idx < n;
         idx += gridDim.x * blockDim.x) {
        unsigned int pr = list[idx];
        int i = (int)(pr >> 11);
        int j = (int)(pr & 2047u);
        if (exact_suppress(cor, areas, i, j))
            atomicOr(&mask[(size_t)i * words + (j >> 6)], 1ULL << (j & 63));
    }
}

// ---------------------------------------------------------------------------
// Kernel B3: overflow fallback (never taken in practice). If the survivor
// list overflowed capacity, redo ALL pairs exactly (idempotent atomicOr).
// ---------------------------------------------------------------------------
__global__ __launch_bounds__(256) void fallback_kernel(
    const double* __restrict__ cor, const double* __restrict__ areas,
    const unsigned int* __restrict__ counter,
    unsigned long long* __restrict__ mask, int N, int words,
    unsigned int cap) {
    if (*counter <= cap) return;
    long long total = (long long)N * N;
    for (long long p = blockIdx.x * blockDim.x + threadIdx.x; p < total;
         p += (long long)gridDim.x * blockDim.x) {
        int i = (int)(p / N);
        int j = (int)(p - (long long)i * N);
        if (j > i && exact_suppress(cor, areas, i, j))
            atomicOr(&mask[(size_t)i * words + (j >> 6)], 1ULL << (j & 63));
    }
}

// ---------------------------------------------------------------------------
// Kernel C: chunked greedy sweep (identical to R2 — isolating this round's
// change; next profile reveals its true cost).
// ---------------------------------------------------------------------------
__global__ __launch_bounds__(64, 1) void greedy_kernel(
    const unsigned long long* __restrict__ mask, int* __restrict__ out,
    int N, int words, int topn) {
    int lane = threadIdx.x;
    unsigned long long removed = 0ULL;

    for (int c = 0; c < words; ++c) {
        int base = c * 64;
        int cnt = N - base;
        unsigned long long rows[64];
#pragma unroll
        for (int i = 0; i < 64; ++i) {
            rows[i] = (i < cnt && lane < words)
                          ? mask[(size_t)(base + i) * words + lane]
                          : 0ULL;
        }
        unsigned long long K = 0ULL;
        if (lane == c) {
            unsigned long long rem = removed;
#pragma unroll
            for (int i = 0; i < 64; ++i) {
                if (!((rem >> i) & 1ULL)) {
                    K |= 1ULL << i;
                    rem |= rows[i];
                }
            }
            removed = rem;
        }
        K = __shfl(K, c);
#pragma unroll
        for (int i = 0; i < 64; ++i) {
            unsigned long long sel = 0ULL - (unsigned long long)((K >> i) & 1ULL);
            removed |= rows[i] & sel;
        }
    }

    unsigned long long keepw = 0ULL;
    if (lane < words) {
        keepw = ~removed;
        int base = lane * 64;
        int valid = N - base;
        if (valid <= 0)
            keepw = 0ULL;
        else if (valid < 64)
            keepw &= ((1ULL << valid) - 1ULL);
    }

    int pc = __popcll(keepw);
    int scan = pc;
#pragma unroll
    for (int off = 1; off < 64; off <<= 1) {
        int v = __shfl_up(scan, off);
        if (lane >= off) scan += v;
    }
    int base_out = scan - pc;
    int total = __shfl(scan, words - 1);

    if (lane < words) {
        int pos = base_out;
        unsigned long long w = keepw;
        while (w) {
            int b = __ffsll(w) - 1;
            w &= w - 1ULL;
            if (pos < topn) out[pos] = lane * 64 + b;
            ++pos;
        }
    }
    for (int k = (total < topn ? total : topn) + lane; k < topn; k += 64)
        out[k] = -1;
}

// ---------------------------------------------------------------------------
extern "C" void kernel_launch(void* const* d_in, const int* in_sizes, int n_in,
                              void* d_out, int out_size, void* d_ws,
                              size_t ws_size, hipStream_t stream) {
    const float* boxes = (const float*)d_in[0];
    int N = in_sizes[0] / 5;      // 2000
    int words = (N + 63) / 64;    // 32
    int topn = out_size;          // 1000

    // workspace layout (16B-aligned chunks)
    char* ws = (char*)d_ws;
    size_t off = 0;
    double* cor = (double*)(ws + off);            off += (size_t)N * 8 * 8;   // 128000
    double* areas = (double*)(ws + off);          off += (size_t)N * 8;       // 16000
    unsigned long long* mask =
        (unsigned long long*)(ws + off);          off += (size_t)N * words * 8; // 512000
    float* aabb = (float*)(ws + off);             off += (size_t)N * 5 * 4;   // 40000
    unsigned int* counter = (unsigned int*)(ws + off); off += 16;
    unsigned int* list = (unsigned int*)(ws + off);
    size_t list_bytes = (ws_size > off) ? (ws_size - off) : 0;
    unsigned int cap = (unsigned int)(list_bytes / 4);
    if (cap > 2100000u) cap = 2100000u;

    corners_kernel<<<(N + 255) / 256, 256, 0, stream>>>(boxes, cor, areas,
                                                        aabb, counter, N);
    bound_kernel<<<N, 256, 0, stream>>>(aabb, mask, list, counter, N, words,
                                        cap);
    exact_kernel<<<128, 256, 0, stream>>>(cor, areas, list, counter, mask,
                                          words, cap);
    fallback_kernel<<<128, 256, 0, stream>>>(cor, areas, counter, mask, N,
                                             words, cap);
    greedy_kernel<<<1, 64, 0, stream>>>(mask, (int*)d_out, N, words, topn);
}

// Round 4
// 109.851 us; speedup vs baseline: 4.4023x; 4.4023x over previous
//
#include <hip/hip_runtime.h>

#define NMS_TH 0.7

// ---------------------------------------------------------------------------
// Kernel A: per-box fp64 corners (CCW) + fp64 areas + fp32 AABB + fp32 area.
// ---------------------------------------------------------------------------
__global__ void corners_kernel(const float* __restrict__ boxes,
                               double* __restrict__ cor,    // N*8
                               double* __restrict__ areas,  // N
                               float* __restrict__ aabb,    // 5*N
                               int N) {
    int i = blockIdx.x * blockDim.x + threadIdx.x;
    if (i >= N) return;
    double xc = boxes[i * 5 + 0];
    double yc = boxes[i * 5 + 1];
    double w  = boxes[i * 5 + 2];
    double h  = boxes[i * 5 + 3];
    double t  = boxes[i * 5 + 4];
    double th = t * 0.017453292519943295;  // pi/180
    double c = cos(th), s = sin(th);
    const double lx[4] = {0.5, -0.5, -0.5, 0.5};
    const double ly[4] = {0.5, 0.5, -0.5, -0.5};
    double xmn = 1e30, xmx = -1e30, ymn = 1e30, ymx = -1e30;
#pragma unroll
    for (int k = 0; k < 4; ++k) {
        double x = xc + lx[k] * w * c - ly[k] * h * s;
        double y = yc + lx[k] * w * s + ly[k] * h * c;
        cor[i * 8 + k * 2 + 0] = x;
        cor[i * 8 + k * 2 + 1] = y;
        xmn = fmin(xmn, x); xmx = fmax(xmx, x);
        ymn = fmin(ymn, y); ymx = fmax(ymx, y);
    }
    areas[i] = w * h;
    aabb[0 * N + i] = (float)xmn;
    aabb[1 * N + i] = (float)xmx;
    aabb[2 * N + i] = (float)ymn;
    aabb[3 * N + i] = (float)ymx;
    aabb[4 * N + i] = (float)(w * h);
}

// ---------------------------------------------------------------------------
// Exact convex-quad intersection area via Green's theorem (fp64, static).
// ---------------------------------------------------------------------------
__device__ __forceinline__ double clip_sum(const double* __restrict__ px,
                                           const double* __restrict__ py,
                                           const double* __restrict__ qx,
                                           const double* __restrict__ qy) {
    double acc = 0.0;
#pragma unroll
    for (int e = 0; e < 4; ++e) {
        double x0 = px[e], y0 = py[e];
        double x1 = px[(e + 1) & 3], y1 = py[(e + 1) & 3];
        double dx = x1 - x0, dy = y1 - y0;
        double t0 = 0.0, t1 = 1.0;
        bool empty = false;
#pragma unroll
        for (int f = 0; f < 4; ++f) {
            double ex0 = qx[f], ey0 = qy[f];
            double ex1 = qx[(f + 1) & 3], ey1 = qy[(f + 1) & 3];
            double edx = ex1 - ex0, edy = ey1 - ey0;
            double f0 = edx * (y0 - ey0) - edy * (x0 - ex0);
            double f1 = edx * (y1 - ey0) - edy * (x1 - ex0);
            double df = f1 - f0;
            if (df > 0.0) {
                t0 = fmax(t0, -f0 / df);
            } else if (df < 0.0) {
                t1 = fmin(t1, -f0 / df);
            } else if (f0 < 0.0) {
                empty = true;
            }
        }
        if (!empty && t0 < t1) {
            double ax = x0 + t0 * dx, ay = y0 + t0 * dy;
            double bx = x0 + t1 * dx, by = y0 + t1 * dy;
            acc += ax * by - bx * ay;
        }
    }
    return acc;
}

__device__ __forceinline__ bool exact_suppress(const double* __restrict__ cor,
                                               const double* __restrict__ areas,
                                               int i, int j) {
    double px[4], py[4], qx[4], qy[4];
#pragma unroll
    for (int k = 0; k < 4; ++k) {
        px[k] = cor[i * 8 + k * 2 + 0];
        py[k] = cor[i * 8 + k * 2 + 1];
        qx[k] = cor[j * 8 + k * 2 + 0];
        qy[k] = cor[j * 8 + k * 2 + 1];
    }
    double inter = 0.5 * (clip_sum(px, py, qx, qy) + clip_sum(qx, qy, px, py));
    inter = fmax(inter, 0.0);
    double uni = areas[i] + areas[j] - inter;
    double iou = inter / fmax(uni, 1e-8);
    return iou > NMS_TH;
}

// ---------------------------------------------------------------------------
// Kernel B (fused): block = row i, 256 threads.
// Phase 1: fp32 AABB upper-bound filter (inter <= min(AABB_inter, a_i, a_j);
//   candidate iff 1.699*ub >= 0.699*(a_i+a_j) — guard band 1e-3 vs 0.7, safe
//   vs exact fp64).  Candidates compacted into LDS via LDS atomicAdd.
// Phase 2: exact fp64 clip on the dense LDS list; suppression bits set via
//   32-bit LDS atomicOr.  NO global atomics anywhere.
// Epilogue: store the row's 32 mask words + per-row nonzero flag byte.
// ---------------------------------------------------------------------------
__global__ __launch_bounds__(256) void iou_fused_kernel(
    const float* __restrict__ aabb, const double* __restrict__ cor,
    const double* __restrict__ areas, unsigned long long* __restrict__ mask,
    unsigned char* __restrict__ flags, int N, int words) {
    __shared__ unsigned short cand[2048];   // j fits in 11 bits; <=N-1 entries
    __shared__ unsigned int lmask32[64];    // 32 u64 words as 64 u32
    __shared__ int cnt;
    __shared__ int supflag;

    int i = blockIdx.x;
    int t = threadIdx.x;
    if (t == 0) { cnt = 0; supflag = 0; }
    if (t < 64) lmask32[t] = 0u;
    __syncthreads();

    float ixmn = aabb[0 * N + i], ixmx = aabb[1 * N + i];
    float iymn = aabb[2 * N + i], iymx = aabb[3 * N + i];
    float iaf = aabb[4 * N + i];

    for (int j = t; j < N; j += 256) {
        if (j <= i) continue;
        float iw = fminf(ixmx, aabb[1 * N + j]) - fmaxf(ixmn, aabb[0 * N + j]);
        float ih = fminf(iymx, aabb[3 * N + j]) - fmaxf(iymn, aabb[2 * N + j]);
        if (iw > 0.0f && ih > 0.0f) {
            float jaf = aabb[4 * N + j];
            float ub = fminf(iw * ih, fminf(iaf, jaf));
            if (1.699f * ub >= 0.699f * (iaf + jaf)) {
                int p = atomicAdd(&cnt, 1);
                cand[p] = (unsigned short)j;
            }
        }
    }
    __syncthreads();

    int n = cnt;
    for (int k = t; k < n; k += 256) {
        int j = (int)cand[k];
        if (exact_suppress(cor, areas, i, j)) {
            atomicOr(&lmask32[j >> 5], 1u << (j & 31));
            supflag = 1;  // benign race
        }
    }
    __syncthreads();

    if (t < words) {
        unsigned long long wv = ((unsigned long long)lmask32[2 * t + 1] << 32) |
                                (unsigned long long)lmask32[2 * t];
        mask[(size_t)i * words + t] = wv;
    }
    if (t == 0) flags[i] = (unsigned char)(supflag != 0);
}

// ---------------------------------------------------------------------------
// Kernel C: sparse greedy sweep.  One wave; lane L owns 'removed' word L.
// Zero rows (no suppression bits) cannot change state -> skip them.  Per
// active 64-chunk: load only the 64x64 diagonal block (1 word/lane); all
// lanes redundantly maintain the chunk's decision word dm (broadcast via
// shfl of diag rows — ~10cy ALU chain per nonzero row, no register hoard);
// then OR in kept nonzero rows' full mask rows with a 2-deep load pipeline.
// ---------------------------------------------------------------------------
__global__ __launch_bounds__(64, 1) void greedy_kernel(
    const unsigned long long* __restrict__ mask,
    const unsigned char* __restrict__ flags, int* __restrict__ out,
    int N, int words, int topn) {
    int lane = threadIdx.x;
    int wl = lane < words ? lane : (words - 1);  // clamped addr lane->word
    unsigned long long removed = 0ULL;

    // Build per-chunk nonzero-row bitmaps: lane c holds chunk c's word.
    unsigned long long nzw = 0ULL;
    for (int c = 0; c < words; ++c) {
        int r = c * 64 + lane;
        unsigned char f = (r < N) ? flags[r] : (unsigned char)0;
        unsigned long long bal = __ballot(f != 0);
        if (lane == c) nzw = bal;
    }

    for (int c = 0; c < words; ++c) {
        unsigned long long bits = __shfl(nzw, c);
        if (!bits) continue;  // uniform: whole chunk untouched, zero loads
        int base = c * 64;
        int rr = base + lane;
        // diagonal block: lane L = row (base+L)'s word c
        unsigned long long diag =
            (rr < N) ? mask[(size_t)rr * words + c] : 0ULL;
        // all lanes redundantly resolve keep decisions for nonzero rows
        unsigned long long dm = __shfl(removed, c);
        unsigned long long K = 0ULL;
        unsigned long long bb = bits;
        while (bb) {
            int b = __ffsll(bb) - 1;
            bb &= bb - 1ULL;
            unsigned long long s = __shfl(diag, b);
            if (!((dm >> b) & 1ULL)) {
                K |= 1ULL << b;
                dm |= s;
            }
        }
        // apply kept nonzero rows (2-deep pipelined loads)
        unsigned long long ap = bits & K;
        if (ap) {
            int b0 = __ffsll(ap) - 1;
            ap &= ap - 1ULL;
            unsigned long long v0 = mask[(size_t)(base + b0) * words + wl];
            while (ap) {
                int b1 = __ffsll(ap) - 1;
                ap &= ap - 1ULL;
                unsigned long long v1 = mask[(size_t)(base + b1) * words + wl];
                removed |= v0;
                v0 = v1;
            }
            removed |= v0;
        }
    }

    // keep mask per lane-owned word, clipped to N bits
    unsigned long long keepw = 0ULL;
    if (lane < words) {
        keepw = ~removed;
        int base = lane * 64;
        int valid = N - base;
        if (valid <= 0)
            keepw = 0ULL;
        else if (valid < 64)
            keepw &= ((1ULL << valid) - 1ULL);
    }

    // exclusive prefix of popcounts across lanes
    int pc = __popcll(keepw);
    int scan = pc;
#pragma unroll
    for (int off = 1; off < 64; off <<= 1) {
        int v = __shfl_up(scan, off);
        if (lane >= off) scan += v;
    }
    int base_out = scan - pc;
    int total = __shfl(scan, words - 1);

    // emit kept indices
    if (lane < words) {
        int pos = base_out;
        unsigned long long w = keepw;
        while (w) {
            int b = __ffsll(w) - 1;
            w &= w - 1ULL;
            if (pos < topn) out[pos] = lane * 64 + b;
            ++pos;
        }
    }
    // pad tail with -1
    for (int k = (total < topn ? total : topn) + lane; k < topn; k += 64)
        out[k] = -1;
}

// ---------------------------------------------------------------------------
extern "C" void kernel_launch(void* const* d_in, const int* in_sizes, int n_in,
                              void* d_out, int out_size, void* d_ws,
                              size_t ws_size, hipStream_t stream) {
    const float* boxes = (const float*)d_in[0];
    int N = in_sizes[0] / 5;      // 2000
    int words = (N + 63) / 64;    // 32
    int topn = out_size;          // 1000

    char* ws = (char*)d_ws;
    size_t off = 0;
    double* cor = (double*)(ws + off);   off += (size_t)N * 8 * 8;      // 128000
    double* areas = (double*)(ws + off); off += (size_t)N * 8;          // 16000
    unsigned long long* mask =
        (unsigned long long*)(ws + off); off += (size_t)N * words * 8;  // 512000
    float* aabb = (float*)(ws + off);    off += (size_t)N * 5 * 4;      // 40000
    unsigned char* flags = (unsigned char*)(ws + off); off += (size_t)N;

    corners_kernel<<<(N + 255) / 256, 256, 0, stream>>>(boxes, cor, areas,
                                                        aabb, N);
    iou_fused_kernel<<<N, 256, 0, stream>>>(aabb, cor, areas, mask, flags, N,
                                            words);
    greedy_kernel<<<1, 64, 0, stream>>>(mask, flags, (int*)d_out, N, words,
                                        topn);
}